// Round 5
// baseline (448.045 us; speedup 1.0000x reference)
//
#include <hip/hip_runtime.h>
#include <hip/hip_bf16.h>
#include <stdint.h>

typedef __bf16 bf16;
typedef __bf16 bf16x8 __attribute__((ext_vector_type(8)));
typedef float floatx4 __attribute__((ext_vector_type(4)));

// fp32 -> bf16 cast, 8 elements/thread. n % 8 == 0.
__global__ __launch_bounds__(256) void cast_f32_bf16(
    const float* __restrict__ in, bf16* __restrict__ out, int n)
{
    int i = (blockIdx.x * 256 + threadIdx.x) * 8;
    if (i >= n) return;
    float4 a = *(const float4*)(in + i);
    float4 b = *(const float4*)(in + i + 4);
    bf16x8 o;
    o[0] = (bf16)a.x; o[1] = (bf16)a.y; o[2] = (bf16)a.z; o[3] = (bf16)a.w;
    o[4] = (bf16)b.x; o[5] = (bf16)b.y; o[6] = (bf16)b.z; o[7] = (bf16)b.w;
    *(bf16x8*)(out + i) = o;
}

__device__ __forceinline__ void load_lds16(const bf16* g, bf16* l) {
    __builtin_amdgcn_global_load_lds(
        (const __attribute__((address_space(1))) void*)g,
        (__attribute__((address_space(3))) void*)l, 16, 0, 0);
}

#define VMCNT(N)  asm volatile("s_waitcnt vmcnt(" #N ")" ::: "memory")
#define LGKM0     do { asm volatile("s_waitcnt lgkmcnt(0)" ::: "memory"); \
                       __builtin_amdgcn_sched_barrier(0); } while (0)
#define BARRIER   do { asm volatile("" ::: "memory");                     \
                       __builtin_amdgcn_s_barrier();                      \
                       asm volatile("" ::: "memory"); } while (0)

// C[m,n] = sum_k A[m,k] * Bt[n,k];  A:[M,K] bf16, Bt:[N,K] bf16.
// M%256==0, N%256==0, K%128==0.
//
// R9: full-rank LDS swizzle. R6/R7/R8 all measured exactly ~4 extra
// conflict-cycles per ds_read_b128 (1.9e7 total) because every variant
// left each 8-consecutive-lane group covering only 2-4 distinct 16B
// slots (b128 octet model: 8 lanes x 16B = 128B = one bank sweep; needs
// 8 distinct slots/octet). Fix: phys_chunk = logical ^ (row & 7) -- a
// full bijection on the octet's row bits, so octet slots = const ^
// {0..7} = all 8. Other row terms (16/32/64 multiples) vanish mod 8 for
// both A and B reads. Staging fetches logical chunk (t&7)^((t>>3)&7)
// into linear dest t*16B (pre-swizzled-global, coalesced within each
// 128B row segment). ks-subtile: phys = (ks*4|kq)^f -> two precomputed
// chunk offsets ck0/ck1 (XOR, not additive).
//
// 8-phase schedule (R8, kept): per K-tile-pair (BK=64 x2), 8 phases;
// each phase = one C quadrant (16x mfma_16x16x32) + one-ahead Gray-order
// ds_read set + one half-tile global_load_lds stage + raw barrier;
// counted vmcnt(2) at phase top (loads cross barriers, never drained to
// 0 in the loop). RAW: min stage->read gap 3 phases vs vmcnt(2)
// guarantee of 2-phase retirement. WAR: >=1 barrier between a region's
// last read and its overwrite, plus ~200cy global-return latency.
template <typename CT>
__global__ __launch_bounds__(512, 2) void gemm_bt(
    const bf16* __restrict__ A, const bf16* __restrict__ Bt, CT* __restrict__ C,
    int M, int N, int K)
{
    // [buf][half][128 rows][64 k] bf16 = 64 KiB each
    __shared__ __align__(16) bf16 As[2 * 16384];
    __shared__ __align__(16) bf16 Bs[2 * 16384];

    const int tid = threadIdx.x;
    const int l   = tid & 63;
    const int w   = tid >> 6;
    const int wm  = w & 1;    // M half (128 rows)
    const int wn  = w >> 1;   // N quarter (64 cols)
    const int rl  = l & 15;
    const int kq  = l >> 4;
    const int swz = rl & 7;                       // full-rank row XOR
    const int ck0 = ((0 + kq) ^ swz) * 8;         // ks=0 phys chunk offset
    const int ck1 = ((4 + kq) ^ swz) * 8;         // ks=1 phys chunk offset

    const int mBase = blockIdx.y * 256;
    const int nBase = blockIdx.x * 256;

    // ds_read bases WITHOUT chunk (elements). A: half=wm, row=msub*64+i*16+rl.
    const int aRd = wm * 8192 + rl * 64;
    // B: half=wn>>1, row=(wn&1)*64+nsub*32+j*16+rl.
    const int bRd = (wn >> 1) * 8192 + ((wn & 1) * 64 + rl) * 64;

    // staging: thread t owns phys slot (row t>>3, chunk t&7) and the same
    // slot at row+64. Global fetches logical chunk (t&7)^((t>>3)&7).
    const int srow = tid >> 3;
    const int schk = (tid & 7) ^ ((tid >> 3) & 7);
    const bf16* gA = A  + (size_t)(mBase + srow) * K + schk * 8;
    const bf16* gB = Bt + (size_t)(nBase + srow) * K + schk * 8;
    bf16* dA = As + tid * 8;
    bf16* dB = Bs + tid * 8;
    const size_t rowK64 = (size_t)64 * K;

#define STAGE_A(T, h, buf) do {                                           \
        const bf16* _g = gA + (size_t)(h) * 128 * K + (T) * 64;           \
        bf16* _d = dA + (buf) * 16384 + (h) * 8192;                       \
        load_lds16(_g, _d);                                               \
        load_lds16(_g + rowK64, _d + 4096);                               \
    } while (0)
#define STAGE_B(T, h, buf) do {                                           \
        const bf16* _g = gB + (size_t)(h) * 128 * K + (T) * 64;           \
        bf16* _d = dB + (buf) * 16384 + (h) * 8192;                       \
        load_lds16(_g, _d);                                               \
        load_lds16(_g + rowK64, _d + 4096);                               \
    } while (0)

#define READ_A(dst, msub, buf) do {                                       \
        _Pragma("unroll")                                                 \
        for (int _i = 0; _i < 4; ++_i) {                                  \
            _Pragma("unroll")                                             \
            for (int _ks = 0; _ks < 2; ++_ks)                             \
                dst[_i][_ks] = *(const bf16x8*)(As + (buf) * 16384 + aRd  \
                    + (msub) * 4096 + _i * 1024 + (_ks ? ck1 : ck0));     \
        }                                                                 \
    } while (0)
#define READ_B(dst, nsub, buf) do {                                       \
        _Pragma("unroll")                                                 \
        for (int _j = 0; _j < 2; ++_j) {                                  \
            _Pragma("unroll")                                             \
            for (int _ks = 0; _ks < 2; ++_ks)                             \
                dst[_j][_ks] = *(const bf16x8*)(Bs + (buf) * 16384 + bRd  \
                    + (nsub) * 2048 + _j * 1024 + (_ks ? ck1 : ck0));     \
        }                                                                 \
    } while (0)

#define MFMA_Q(am, bn, MS, NS) do {                                       \
        __builtin_amdgcn_s_setprio(1);                                    \
        _Pragma("unroll")                                                 \
        for (int _ks = 0; _ks < 2; ++_ks)                                 \
            _Pragma("unroll")                                             \
            for (int _i = 0; _i < 4; ++_i)                                \
                _Pragma("unroll")                                         \
                for (int _j = 0; _j < 2; ++_j)                            \
                    acc[(MS)*4 + _i][(NS)*2 + _j] =                       \
                        __builtin_amdgcn_mfma_f32_16x16x32_bf16(          \
                            am[_i][_ks], bn[_j][_ks],                     \
                            acc[(MS)*4 + _i][(NS)*2 + _j], 0, 0, 0);      \
        __builtin_amdgcn_s_setprio(0);                                    \
    } while (0)

    floatx4 acc[8][4] = {};
    bf16x8 a0[4][2], a1[4][2], b0[2][2], b1[2][2];

    const int kIters = K >> 7;   // pairs of 64-wide K-tiles
    const int nT     = K >> 6;   // 64-wide K-tiles

    // ---- prologue: stages #1..#7 (steady-state issue-order suffix)
    STAGE_B(0, 0, 0);    // #1 buf0.B.h0  (tile 0)
    STAGE_A(0, 0, 0);    // #2 buf0.A.h0
    STAGE_A(0, 1, 0);    // #3 buf0.A.h1
    STAGE_B(0, 1, 0);    // #4 buf0.B.h1
    STAGE_B(1, 0, 1);    // #5 buf1.B.h0  (tile 1)
    STAGE_A(1, 0, 1);    // #6 buf1.A.h0
    STAGE_A(1, 1, 1);    // #7 buf1.A.h1
    VMCNT(2);            // 12 of 14 loads retired: #1..#6 done
    BARRIER;
    READ_A(a0, 0, 0);
    READ_B(b0, 0, 0);

    for (int it = 0; it < kIters; ++it) {
        const int To  = 2 * it + 1;
        int Te2 = 2 * it + 2; if (Te2 >= nT) Te2 -= nT;   // wrap: dead data
        int To2 = 2 * it + 3; if (To2 >= nT) To2 -= nT;

        // ph e0: MFMA (A0,B0) of even tile; read B1(e); stage buf1.B.h1(o)
        VMCNT(2); READ_B(b1, 1, 0); STAGE_B(To, 1, 1);
        BARRIER; LGKM0; MFMA_Q(a0, b0, 0, 0);
        // ph e1: MFMA (A0,B1); read A1(e); stage buf0.B.h0(e2)
        VMCNT(2); READ_A(a1, 1, 0); STAGE_B(Te2, 0, 0);
        BARRIER; LGKM0; MFMA_Q(a0, b1, 0, 1);
        // ph e2: MFMA (A1,B1); read A0'(o, buf1); stage buf0.A.h0(e2)
        VMCNT(2); READ_A(a0, 0, 1); STAGE_A(Te2, 0, 0);
        BARRIER; LGKM0; MFMA_Q(a1, b1, 1, 1);
        // ph e3: MFMA (A1,B0); read B1'(o); stage buf0.A.h1(e2)
        VMCNT(2); READ_B(b1, 1, 1); STAGE_A(Te2, 1, 0);
        BARRIER; LGKM0; MFMA_Q(a1, b0, 1, 0);
        // ph o0: MFMA (A0',B1'); read B0'(o); stage buf0.B.h1(e2)
        VMCNT(2); READ_B(b0, 0, 1); STAGE_B(Te2, 1, 0);
        BARRIER; LGKM0; MFMA_Q(a0, b1, 0, 1);
        // ph o1: MFMA (A0',B0'); read A1'(o); stage buf1.B.h0(o2)
        VMCNT(2); READ_A(a1, 1, 1); STAGE_B(To2, 0, 1);
        BARRIER; LGKM0; MFMA_Q(a0, b0, 0, 0);
        // ph o2: MFMA (A1',B0'); read A0''(e2, buf0); stage buf1.A.h0(o2)
        VMCNT(2); READ_A(a0, 0, 0); STAGE_A(To2, 0, 1);
        BARRIER; LGKM0; MFMA_Q(a1, b0, 1, 0);
        // ph o3: MFMA (A1',B1'); read B0''(e2); stage buf1.A.h1(o2)
        VMCNT(2); READ_B(b0, 0, 0); STAGE_A(To2, 1, 1);
        BARRIER; LGKM0; MFMA_Q(a1, b1, 1, 1);
    }

#undef STAGE_A
#undef STAGE_B
#undef READ_A
#undef READ_B
#undef MFMA_Q

    // C/D (16x16): col = lane&15, row = (lane>>4)*4 + reg
    #pragma unroll
    for (int fi = 0; fi < 8; ++fi) {
        #pragma unroll
        for (int fj = 0; fj < 4; ++fj) {
            const int col = nBase + wn * 64 + fj * 16 + rl;
            const int rB  = mBase + wm * 128 + fi * 16 + kq * 4;
            #pragma unroll
            for (int r = 0; r < 4; ++r)
                C[(size_t)(rB + r) * N + col] = (CT)acc[fi][fj][r];
        }
    }
}

// BCx: [8192, 6144] bf16 (cols 0:2048=B, 2048:4096=C, 4096:6144=x)
// convw: [2048, 3] fp32;  Y: [8192, 2048] bf16
// y[b,s,h] = C * (w0*Bx[s-2] + w1*Bx[s-1] + w2*Bx[s]),  Bx = B*x, causal.
__global__ __launch_bounds__(256) void conv_gate(
    const bf16* __restrict__ BCx, const float* __restrict__ convw,
    bf16* __restrict__ Y)
{
    const int tx = threadIdx.x;
    const int h0 = tx * 8;
    const int bb = blockIdx.y;
    const int s0 = blockIdx.x * 32;

    float w0[8], w1[8], w2[8];
    #pragma unroll
    for (int j = 0; j < 8; ++j) {
        w0[j] = convw[(h0 + j) * 3 + 0];
        w1[j] = convw[(h0 + j) * 3 + 1];
        w2[j] = convw[(h0 + j) * 3 + 2];
    }

    const size_t mB = (size_t)bb * 4096;

    float bx1[8], bx2[8];
    #pragma unroll
    for (int j = 0; j < 8; ++j) { bx1[j] = 0.f; bx2[j] = 0.f; }
    if (s0 >= 2) {
        const bf16* r1 = BCx + (mB + s0 - 1) * 6144;
        const bf16* r2 = BCx + (mB + s0 - 2) * 6144;
        bf16x8 B1 = *(const bf16x8*)(r1 + h0);
        bf16x8 x1 = *(const bf16x8*)(r1 + 4096 + h0);
        bf16x8 B2 = *(const bf16x8*)(r2 + h0);
        bf16x8 x2 = *(const bf16x8*)(r2 + 4096 + h0);
        #pragma unroll
        for (int j = 0; j < 8; ++j) {
            bx1[j] = (float)B1[j] * (float)x1[j];
            bx2[j] = (float)B2[j] * (float)x2[j];
        }
    }

    for (int s = s0; s < s0 + 32; ++s) {
        const size_t m = mB + s;
        const bf16* rp = BCx + m * 6144;
        bf16x8 Bv = *(const bf16x8*)(rp + h0);
        bf16x8 Cv = *(const bf16x8*)(rp + 2048 + h0);
        bf16x8 xv = *(const bf16x8*)(rp + 4096 + h0);
        bf16x8 o;
        #pragma unroll
        for (int j = 0; j < 8; ++j) {
            float bx0 = (float)Bv[j] * (float)xv[j];
            float cv  = w0[j] * bx2[j] + w1[j] * bx1[j] + w2[j] * bx0;
            o[j] = (bf16)((float)Cv[j] * cv);
            bx2[j] = bx1[j];
            bx1[j] = bx0;
        }
        *(bf16x8*)(Y + m * 2048 + h0) = o;
    }
}

extern "C" void kernel_launch(void* const* d_in, const int* in_sizes, int n_in,
                              void* d_out, int out_size, void* d_ws, size_t ws_size,
                              hipStream_t stream) {
    const float* hidden = (const float*)d_in[0];   // [2,4096,2048] fp32
    const float* Win    = (const float*)d_in[1];   // [6144,2048]  fp32 (B^T layout)
    const float* convw  = (const float*)d_in[2];   // [2048,1,3]   fp32
    const float* Wout   = (const float*)d_in[3];   // [2048,2048]  fp32 (B^T layout)
    float* out = (float*)d_out;                    // [8192,2048]  fp32

    const int nH = 8192 * 2048;
    const int nWin = 6144 * 2048;
    const int nWout = 2048 * 2048;

    bf16* hB    = (bf16*)d_ws;                       // 32 MiB
    bf16* WinB  = hB + (size_t)nH;                   // 24 MiB
    bf16* WoutB = WinB + (size_t)nWin;               //  8 MiB
    bf16* BCx   = WoutB + (size_t)nWout;             // 96 MiB
    bf16* Y     = BCx + (size_t)8192 * 6144;         // 32 MiB

    cast_f32_bf16<<<nH / (256 * 8), 256, 0, stream>>>(hidden, hB, nH);
    cast_f32_bf16<<<nWin / (256 * 8), 256, 0, stream>>>(Win, WinB, nWin);
    cast_f32_bf16<<<nWout / (256 * 8), 256, 0, stream>>>(Wout, WoutB, nWout);

    gemm_bt<bf16><<<dim3(6144 / 256, 8192 / 256), dim3(512), 0, stream>>>(
        hB, WinB, BCx, 8192, 6144, 2048);
    conv_gate<<<dim3(4096 / 32, 2), dim3(256), 0, stream>>>(BCx, convw, Y);
    gemm_bt<float><<<dim3(2048 / 256, 8192 / 256), dim3(512), 0, stream>>>(
        Y, WoutB, out, 8192, 2048, 2048);
}

// Round 6
// 432.545 us; speedup vs baseline: 1.0358x; 1.0358x over previous
//
#include <hip/hip_runtime.h>
#include <hip/hip_bf16.h>
#include <stdint.h>

typedef __bf16 bf16;
typedef __bf16 bf16x8 __attribute__((ext_vector_type(8)));
typedef float floatx4 __attribute__((ext_vector_type(4)));

// fp32 -> bf16 cast, 8 elements/thread. n % 8 == 0.
__global__ __launch_bounds__(256) void cast_f32_bf16(
    const float* __restrict__ in, bf16* __restrict__ out, int n)
{
    int i = (blockIdx.x * 256 + threadIdx.x) * 8;
    if (i >= n) return;
    float4 a = *(const float4*)(in + i);
    float4 b = *(const float4*)(in + i + 4);
    bf16x8 o;
    o[0] = (bf16)a.x; o[1] = (bf16)a.y; o[2] = (bf16)a.z; o[3] = (bf16)a.w;
    o[4] = (bf16)b.x; o[5] = (bf16)b.y; o[6] = (bf16)b.z; o[7] = (bf16)b.w;
    *(bf16x8*)(out + i) = o;
}

__device__ __forceinline__ void load_lds16(const bf16* g, bf16* l) {
    __builtin_amdgcn_global_load_lds(
        (const __attribute__((address_space(1))) void*)g,
        (__attribute__((address_space(3))) void*)l, 16, 0, 0);
}

#define VMCNT(N)  asm volatile("s_waitcnt vmcnt(" #N ")" ::: "memory")
#define BARRIER   do { asm volatile("" ::: "memory");                     \
                       __builtin_amdgcn_s_barrier();                      \
                       asm volatile("" ::: "memory"); } while (0)

// C[m,n] = sum_k A[m,k] * Bt[n,k];  A:[M,K] bf16, Bt:[N,K] bf16.
// M%256==0, N%256==0, K%128==0.
//
// R10: drop the forced lgkmcnt(0). R9's phase did {read(p+1); stage;
// barrier; lgkmcnt(0); mfma(p)} -- the lgkmcnt(0) drained the reads
// JUST issued this phase, exposing the whole 8-wave read queue (~576cy)
// serially before each MFMA burst (~620cy): per-iter 9625cy == LDS+MFMA
// SUM (no overlap). The compiler's own dataflow waits are counted
// (mfma(p) uses regs loaded at p-1 -> it emits lgkmcnt(R_p) allowing
// this phase's reads to stay outstanding), so deleting the forced drain
// overlaps read-drain with MFMA. RAW on staged LDS data is via
// vmcnt(2)+barrier (unchanged; min stage->read gap 3 phases). s_barrier
// does not require drained counters. WAR: reads can't cross the barrier
// memory clobber; overwriting stage's LDS write lands >=1 barrier +
// ~600cy later.
//
// R9 swizzle (kept, verified 0 conflicts): phys_chunk = logical ^
// (row & 7) -- full bijection per 8-lane octet (b128 octet model: 8
// lanes x 16B = one bank sweep; needs 8 distinct slots). Staging
// fetches logical chunk (t&7)^((t>>3)&7) into linear dest t*16B.
//
// 8-phase schedule (R8, kept): per K-tile-pair (BK=64 x2), 8 phases;
// each phase = one C quadrant (16x mfma_16x16x32) + one-ahead Gray-order
// ds_read set + one half-tile global_load_lds stage + raw barrier;
// counted vmcnt(2) at phase top (loads cross barriers, never drained to
// 0 in the loop).
template <typename CT>
__global__ __launch_bounds__(512, 2) void gemm_bt(
    const bf16* __restrict__ A, const bf16* __restrict__ Bt, CT* __restrict__ C,
    int M, int N, int K)
{
    // [buf][half][128 rows][64 k] bf16 = 64 KiB each
    __shared__ __align__(16) bf16 As[2 * 16384];
    __shared__ __align__(16) bf16 Bs[2 * 16384];

    const int tid = threadIdx.x;
    const int l   = tid & 63;
    const int w   = tid >> 6;
    const int wm  = w & 1;    // M half (128 rows)
    const int wn  = w >> 1;   // N quarter (64 cols)
    const int rl  = l & 15;
    const int kq  = l >> 4;
    const int swz = rl & 7;                       // full-rank row XOR
    const int ck0 = ((0 + kq) ^ swz) * 8;         // ks=0 phys chunk offset
    const int ck1 = ((4 + kq) ^ swz) * 8;         // ks=1 phys chunk offset

    const int mBase = blockIdx.y * 256;
    const int nBase = blockIdx.x * 256;

    // ds_read bases WITHOUT chunk (elements). A: half=wm, row=msub*64+i*16+rl.
    const int aRd = wm * 8192 + rl * 64;
    // B: half=wn>>1, row=(wn&1)*64+nsub*32+j*16+rl.
    const int bRd = (wn >> 1) * 8192 + ((wn & 1) * 64 + rl) * 64;

    // staging: thread t owns phys slot (row t>>3, chunk t&7) and the same
    // slot at row+64. Global fetches logical chunk (t&7)^((t>>3)&7).
    const int srow = tid >> 3;
    const int schk = (tid & 7) ^ ((tid >> 3) & 7);
    const bf16* gA = A  + (size_t)(mBase + srow) * K + schk * 8;
    const bf16* gB = Bt + (size_t)(nBase + srow) * K + schk * 8;
    bf16* dA = As + tid * 8;
    bf16* dB = Bs + tid * 8;
    const size_t rowK64 = (size_t)64 * K;

#define STAGE_A(T, h, buf) do {                                           \
        const bf16* _g = gA + (size_t)(h) * 128 * K + (T) * 64;           \
        bf16* _d = dA + (buf) * 16384 + (h) * 8192;                       \
        load_lds16(_g, _d);                                               \
        load_lds16(_g + rowK64, _d + 4096);                               \
    } while (0)
#define STAGE_B(T, h, buf) do {                                           \
        const bf16* _g = gB + (size_t)(h) * 128 * K + (T) * 64;           \
        bf16* _d = dB + (buf) * 16384 + (h) * 8192;                       \
        load_lds16(_g, _d);                                               \
        load_lds16(_g + rowK64, _d + 4096);                               \
    } while (0)

#define READ_A(dst, msub, buf) do {                                       \
        _Pragma("unroll")                                                 \
        for (int _i = 0; _i < 4; ++_i) {                                  \
            _Pragma("unroll")                                             \
            for (int _ks = 0; _ks < 2; ++_ks)                             \
                dst[_i][_ks] = *(const bf16x8*)(As + (buf) * 16384 + aRd  \
                    + (msub) * 4096 + _i * 1024 + (_ks ? ck1 : ck0));     \
        }                                                                 \
    } while (0)
#define READ_B(dst, nsub, buf) do {                                       \
        _Pragma("unroll")                                                 \
        for (int _j = 0; _j < 2; ++_j) {                                  \
            _Pragma("unroll")                                             \
            for (int _ks = 0; _ks < 2; ++_ks)                             \
                dst[_j][_ks] = *(const bf16x8*)(Bs + (buf) * 16384 + bRd  \
                    + (nsub) * 2048 + _j * 1024 + (_ks ? ck1 : ck0));     \
        }                                                                 \
    } while (0)

#define MFMA_Q(am, bn, MS, NS) do {                                       \
        __builtin_amdgcn_s_setprio(1);                                    \
        _Pragma("unroll")                                                 \
        for (int _ks = 0; _ks < 2; ++_ks)                                 \
            _Pragma("unroll")                                             \
            for (int _i = 0; _i < 4; ++_i)                                \
                _Pragma("unroll")                                         \
                for (int _j = 0; _j < 2; ++_j)                            \
                    acc[(MS)*4 + _i][(NS)*2 + _j] =                       \
                        __builtin_amdgcn_mfma_f32_16x16x32_bf16(          \
                            am[_i][_ks], bn[_j][_ks],                     \
                            acc[(MS)*4 + _i][(NS)*2 + _j], 0, 0, 0);      \
        __builtin_amdgcn_s_setprio(0);                                    \
    } while (0)

    floatx4 acc[8][4] = {};
    bf16x8 a0[4][2], a1[4][2], b0[2][2], b1[2][2];

    const int kIters = K >> 7;   // pairs of 64-wide K-tiles
    const int nT     = K >> 6;   // 64-wide K-tiles

    // ---- prologue: stages #1..#7 (steady-state issue-order suffix)
    STAGE_B(0, 0, 0);    // #1 buf0.B.h0  (tile 0)
    STAGE_A(0, 0, 0);    // #2 buf0.A.h0
    STAGE_A(0, 1, 0);    // #3 buf0.A.h1
    STAGE_B(0, 1, 0);    // #4 buf0.B.h1
    STAGE_B(1, 0, 1);    // #5 buf1.B.h0  (tile 1)
    STAGE_A(1, 0, 1);    // #6 buf1.A.h0
    STAGE_A(1, 1, 1);    // #7 buf1.A.h1
    VMCNT(2);            // 12 of 14 loads retired: #1..#6 done
    BARRIER;
    READ_A(a0, 0, 0);
    READ_B(b0, 0, 0);

    for (int it = 0; it < kIters; ++it) {
        const int To  = 2 * it + 1;
        int Te2 = 2 * it + 2; if (Te2 >= nT) Te2 -= nT;   // wrap: dead data
        int To2 = 2 * it + 3; if (To2 >= nT) To2 -= nT;

        // ph e0: MFMA (A0,B0) of even tile; read B1(e); stage buf1.B.h1(o)
        VMCNT(2); READ_B(b1, 1, 0); STAGE_B(To, 1, 1);
        BARRIER; MFMA_Q(a0, b0, 0, 0);
        // ph e1: MFMA (A0,B1); read A1(e); stage buf0.B.h0(e2)
        VMCNT(2); READ_A(a1, 1, 0); STAGE_B(Te2, 0, 0);
        BARRIER; MFMA_Q(a0, b1, 0, 1);
        // ph e2: MFMA (A1,B1); read A0'(o, buf1); stage buf0.A.h0(e2)
        VMCNT(2); READ_A(a0, 0, 1); STAGE_A(Te2, 0, 0);
        BARRIER; MFMA_Q(a1, b1, 1, 1);
        // ph e3: MFMA (A1,B0); read B1'(o); stage buf0.A.h1(e2)
        VMCNT(2); READ_B(b1, 1, 1); STAGE_A(Te2, 1, 0);
        BARRIER; MFMA_Q(a1, b0, 1, 0);
        // ph o0: MFMA (A0',B1'); read B0'(o); stage buf0.B.h1(e2)
        VMCNT(2); READ_B(b0, 0, 1); STAGE_B(Te2, 1, 0);
        BARRIER; MFMA_Q(a0, b1, 0, 1);
        // ph o1: MFMA (A0',B0'); read A1'(o); stage buf1.B.h0(o2)
        VMCNT(2); READ_A(a1, 1, 1); STAGE_B(To2, 0, 1);
        BARRIER; MFMA_Q(a0, b0, 0, 0);
        // ph o2: MFMA (A1',B0'); read A0''(e2, buf0); stage buf1.A.h0(o2)
        VMCNT(2); READ_A(a0, 0, 0); STAGE_A(To2, 0, 1);
        BARRIER; MFMA_Q(a1, b0, 1, 0);
        // ph o3: MFMA (A1',B1'); read B0''(e2); stage buf1.A.h1(o2)
        VMCNT(2); READ_B(b0, 0, 0); STAGE_A(To2, 1, 1);
        BARRIER; MFMA_Q(a1, b1, 1, 1);
    }

#undef STAGE_A
#undef STAGE_B
#undef READ_A
#undef READ_B
#undef MFMA_Q

    // C/D (16x16): col = lane&15, row = (lane>>4)*4 + reg
    #pragma unroll
    for (int fi = 0; fi < 8; ++fi) {
        #pragma unroll
        for (int fj = 0; fj < 4; ++fj) {
            const int col = nBase + wn * 64 + fj * 16 + rl;
            const int rB  = mBase + wm * 128 + fi * 16 + kq * 4;
            #pragma unroll
            for (int r = 0; r < 4; ++r)
                C[(size_t)(rB + r) * N + col] = (CT)acc[fi][fj][r];
        }
    }
}

// BCx: [8192, 6144] bf16 (cols 0:2048=B, 2048:4096=C, 4096:6144=x)
// convw: [2048, 3] fp32;  Y: [8192, 2048] bf16
// y[b,s,h] = C * (w0*Bx[s-2] + w1*Bx[s-1] + w2*Bx[s]),  Bx = B*x, causal.
__global__ __launch_bounds__(256) void conv_gate(
    const bf16* __restrict__ BCx, const float* __restrict__ convw,
    bf16* __restrict__ Y)
{
    const int tx = threadIdx.x;
    const int h0 = tx * 8;
    const int bb = blockIdx.y;
    const int s0 = blockIdx.x * 32;

    float w0[8], w1[8], w2[8];
    #pragma unroll
    for (int j = 0; j < 8; ++j) {
        w0[j] = convw[(h0 + j) * 3 + 0];
        w1[j] = convw[(h0 + j) * 3 + 1];
        w2[j] = convw[(h0 + j) * 3 + 2];
    }

    const size_t mB = (size_t)bb * 4096;

    float bx1[8], bx2[8];
    #pragma unroll
    for (int j = 0; j < 8; ++j) { bx1[j] = 0.f; bx2[j] = 0.f; }
    if (s0 >= 2) {
        const bf16* r1 = BCx + (mB + s0 - 1) * 6144;
        const bf16* r2 = BCx + (mB + s0 - 2) * 6144;
        bf16x8 B1 = *(const bf16x8*)(r1 + h0);
        bf16x8 x1 = *(const bf16x8*)(r1 + 4096 + h0);
        bf16x8 B2 = *(const bf16x8*)(r2 + h0);
        bf16x8 x2 = *(const bf16x8*)(r2 + 4096 + h0);
        #pragma unroll
        for (int j = 0; j < 8; ++j) {
            bx1[j] = (float)B1[j] * (float)x1[j];
            bx2[j] = (float)B2[j] * (float)x2[j];
        }
    }

    for (int s = s0; s < s0 + 32; ++s) {
        const size_t m = mB + s;
        const bf16* rp = BCx + m * 6144;
        bf16x8 Bv = *(const bf16x8*)(rp + h0);
        bf16x8 Cv = *(const bf16x8*)(rp + 2048 + h0);
        bf16x8 xv = *(const bf16x8*)(rp + 4096 + h0);
        bf16x8 o;
        #pragma unroll
        for (int j = 0; j < 8; ++j) {
            float bx0 = (float)Bv[j] * (float)xv[j];
            float cv  = w0[j] * bx2[j] + w1[j] * bx1[j] + w2[j] * bx0;
            o[j] = (bf16)((float)Cv[j] * cv);
            bx2[j] = bx1[j];
            bx1[j] = bx0;
        }
        *(bf16x8*)(Y + m * 2048 + h0) = o;
    }
}

extern "C" void kernel_launch(void* const* d_in, const int* in_sizes, int n_in,
                              void* d_out, int out_size, void* d_ws, size_t ws_size,
                              hipStream_t stream) {
    const float* hidden = (const float*)d_in[0];   // [2,4096,2048] fp32
    const float* Win    = (const float*)d_in[1];   // [6144,2048]  fp32 (B^T layout)
    const float* convw  = (const float*)d_in[2];   // [2048,1,3]   fp32
    const float* Wout   = (const float*)d_in[3];   // [2048,2048]  fp32 (B^T layout)
    float* out = (float*)d_out;                    // [8192,2048]  fp32

    const int nH = 8192 * 2048;
    const int nWin = 6144 * 2048;
    const int nWout = 2048 * 2048;

    bf16* hB    = (bf16*)d_ws;                       // 32 MiB
    bf16* WinB  = hB + (size_t)nH;                   // 24 MiB
    bf16* WoutB = WinB + (size_t)nWin;               //  8 MiB
    bf16* BCx   = WoutB + (size_t)nWout;             // 96 MiB
    bf16* Y     = BCx + (size_t)8192 * 6144;         // 32 MiB

    cast_f32_bf16<<<nH / (256 * 8), 256, 0, stream>>>(hidden, hB, nH);
    cast_f32_bf16<<<nWin / (256 * 8), 256, 0, stream>>>(Win, WinB, nWin);
    cast_f32_bf16<<<nWout / (256 * 8), 256, 0, stream>>>(Wout, WoutB, nWout);

    gemm_bt<bf16><<<dim3(6144 / 256, 8192 / 256), dim3(512), 0, stream>>>(
        hB, WinB, BCx, 8192, 6144, 2048);
    conv_gate<<<dim3(4096 / 32, 2), dim3(256), 0, stream>>>(BCx, convw, Y);
    gemm_bt<float><<<dim3(2048 / 256, 8192 / 256), dim3(512), 0, stream>>>(
        Y, WoutB, out, 8192, 2048, 2048);
}